// Round 1
// baseline (606.319 us; speedup 1.0000x reference)
//
#include <hip/hip_runtime.h>
#include <hip/hip_bf16.h>
#include <math.h>

#define EPS 1e-5f

typedef __attribute__((ext_vector_type(8))) _Float16 half8;
typedef __attribute__((ext_vector_type(4))) float f32x4;

static __device__ __forceinline__ unsigned short f16u(float x) {
  _Float16 h = (_Float16)x;  // RTN
  return *(unsigned short*)&h;
}
static __device__ __forceinline__ float uf16(unsigned short u) {
  _Float16 h = *(_Float16*)&u;
  return (float)h;
}

// ---------------- Combined weight transform for conv2+conv3: -> B^T f16 padded ----------------
__global__ __launch_bounds__(256) void kWTB2(const float* __restrict__ w2,
    const float* __restrict__ w3, unsigned short* __restrict__ o2,
    unsigned short* __restrict__ o3) {
  int idx = blockIdx.x * 256 + threadIdx.x;
  if (idx < 64 * 104) {
    int oc = idx / 104, kp = idx % 104;
    float v = 0.f;
    if (kp < 96) { int k = kp >> 5, ci = kp & 31; v = w2[oc * 96 + ci * 3 + k]; }
    o2[idx] = f16u(v);
  } else {
    int j = idx - 64 * 104;
    if (j < 128 * 200) {
      int oc = j / 200, kp = j % 200;
      float v = 0.f;
      if (kp < 192) { int k = kp >> 6, ci = kp & 63; v = w3[oc * 192 + ci * 3 + k]; }
      o3[j] = f16u(v);
    }
  }
}

// ---------------- Fused conv1(+bn1+leaky+pool) in-register + conv2 MFMA (+bn2+leaky+pool) ----------------
// x [256][4096][2] -> out2 f16 [256][1022][64]
__global__ __launch_bounds__(512) void kConv12(const float* __restrict__ x,
    const float* __restrict__ w1a, const float* __restrict__ w1b,
    const float* __restrict__ g1, const float* __restrict__ b1,
    const float* __restrict__ m1, const float* __restrict__ v1,
    const unsigned short* __restrict__ Bw, const float* __restrict__ g2,
    const float* __restrict__ b2, const float* __restrict__ m2,
    const float* __restrict__ v2, unsigned short* __restrict__ out2) {
  __shared__ _Float16 sA[130 * 40];
  __shared__ _Float16 sB[64 * 104];
  int tid = threadIdx.x;
  int b = blockIdx.z;
  int p0 = blockIdx.x * 128;  // conv2 pre-pool row base (= conv1-pooled row index)
  // stage conv2 weights
  {
    const unsigned int* src = (const unsigned int*)Bw;
    unsigned int* dst = (unsigned int*)sB;
    for (int i = tid; i < 64 * 104 / 2; i += 512) dst[i] = src[i];
  }
  // compute conv1 + bn1 + leaky + pool directly into sA (f16)
  {
    int c = tid & 31, rg = tid >> 5;  // rg in [0,16)
    float sc1 = g1[c] * rsqrtf(v1[c] + EPS);
    float sh1 = b1[c] - m1[c] * sc1;
    float wk0[4], wk1[4];
    if (c < 16) {
#pragma unroll
      for (int k = 0; k < 4; k++) { wk0[k] = w1a[c * 8 + k]; wk1[k] = w1a[c * 8 + 4 + k]; }
    } else {
      int cc = c - 16;
#pragma unroll
      for (int k = 0; k < 2; k++) { wk0[k] = w1b[cc * 4 + k]; wk1[k] = w1b[cc * 4 + 2 + k]; }
      wk0[2] = wk0[3] = wk1[2] = wk1[3] = 0.f;
    }
    const float2* xp = (const float2*)(x + (size_t)b * 8192);
    for (int r = rg; r < 130; r += 16) {
      int rr = p0 + r;
      _Float16 outv = (_Float16)0.f;
      if (rr < 2047) {
        float xv0[5], xv1[5];
#pragma unroll
        for (int j = 0; j < 5; j++) {
          int l = 2 * rr - 1 + j;
          if (l >= 0 && l < 4096) { float2 v = xp[l]; xv0[j] = v.x; xv1[j] = v.y; }
          else { xv0[j] = 0.f; xv1[j] = 0.f; }
        }
        float a0 = 0.f, a1 = 0.f;
        if (c < 16) {
#pragma unroll
          for (int k = 0; k < 4; k++) {
            a0 += xv0[k] * wk0[k] + xv1[k] * wk1[k];
            a1 += xv0[k + 1] * wk0[k] + xv1[k + 1] * wk1[k];
          }
        } else {
#pragma unroll
          for (int k = 0; k < 2; k++) {
            a0 += xv0[k + 1] * wk0[k] + xv1[k + 1] * wk1[k];
            a1 += xv0[k + 2] * wk0[k] + xv1[k + 2] * wk1[k];
          }
        }
        a0 = a0 * sc1 + sh1; a1 = a1 * sc1 + sh1;
        a0 = a0 >= 0.f ? a0 : 0.01f * a0;
        a1 = a1 >= 0.f ? a1 : 0.01f * a1;
        outv = (_Float16)fmaxf(a0, a1);
      }
      sA[r * 40 + c] = outv;
    }
  }
  __syncthreads();
  // conv2 MFMA: M=128 pre-pool rows, N=64, K=96
  int lane = tid & 63, w = tid >> 6;
  int nrow = lane & 15, quad = lane >> 4;
  f32x4 acc[4];
#pragma unroll
  for (int i = 0; i < 4; i++) acc[i] = (f32x4){0.f, 0.f, 0.f, 0.f};
  int mbase = w * 16;
#pragma unroll
  for (int kk = 0; kk < 3; kk++) {
    half8 a = *(const half8*)(sA + (mbase + nrow + kk) * 40 + quad * 8);
#pragma unroll
    for (int ot = 0; ot < 4; ot++) {
      half8 bb = *(const half8*)(sB + (ot * 16 + nrow) * 104 + kk * 32 + quad * 8);
      acc[ot] = __builtin_amdgcn_mfma_f32_16x16x32_f16(a, bb, acc[ot], 0, 0, 0);
    }
  }
  int gm0 = p0 + mbase + quad * 4;
#pragma unroll
  for (int ot = 0; ot < 4; ot++) {
    int oc = ot * 16 + nrow;
    float sc = g2[oc] * rsqrtf(v2[oc] + EPS);
    float sh = b2[oc] - m2[oc] * sc;
    float v0 = acc[ot][0] * sc + sh, vv1 = acc[ot][1] * sc + sh;
    float v2e = acc[ot][2] * sc + sh, v3 = acc[ot][3] * sc + sh;
    v0 = v0 >= 0.f ? v0 : 0.01f * v0;
    vv1 = vv1 >= 0.f ? vv1 : 0.01f * vv1;
    v2e = v2e >= 0.f ? v2e : 0.01f * v2e;
    v3 = v3 >= 0.f ? v3 : 0.01f * v3;
    float pA = fmaxf(v0, vv1), pB = fmaxf(v2e, v3);
    int t0 = gm0 >> 1, t1 = t0 + 1;
    if (t0 < 1022) out2[((size_t)b * 1022 + t0) * 64 + oc] = f16u(pA);
    if (t1 < 1022) out2[((size_t)b * 1022 + t1) * 64 + oc] = f16u(pB);
  }
}

// ---------------- MFMA conv3 + bn + leaky + pool + LayerNorm fused -> xn f16 [b][t][128], elast ----------------
__global__ __launch_bounds__(512) void kConv3LN(const unsigned short* __restrict__ in,
    const unsigned short* __restrict__ Bw, const float* __restrict__ g,
    const float* __restrict__ bta, const float* __restrict__ mn,
    const float* __restrict__ vr, const float* __restrict__ lnw,
    unsigned short* __restrict__ xn, float* __restrict__ elast) {
  constexpr int IC = 64, OC = 128, LIN = 1022, AP = 72, BP = 200, KSTEPS = 6, OCT = 8;
  __shared__ _Float16 sA[130 * AP];
  __shared__ _Float16 sB[OC * BP];
  int tid = threadIdx.x;
  int b = blockIdx.z;
  int p0 = blockIdx.x * 128;
  {
    const unsigned int* src = (const unsigned int*)Bw;
    unsigned int* dst = (unsigned int*)sB;
    for (int i = tid; i < OC * BP / 2; i += 512) dst[i] = src[i];
  }
  {
    int q = tid % 8;
    for (int r = tid / 8; r < 130; r += 64) {
      int gp = p0 + r;
      uint4 val = {0u, 0u, 0u, 0u};
      if (gp < LIN) val = *(const uint4*)(in + ((size_t)b * LIN + gp) * IC + q * 8);
      *(uint4*)(sA + r * AP + q * 8) = val;
    }
  }
  __syncthreads();
  int lane = tid & 63, w = tid >> 6;
  int nrow = lane & 15, quad = lane >> 4;
  f32x4 acc[OCT];
#pragma unroll
  for (int i = 0; i < OCT; i++) acc[i] = (f32x4){0.f, 0.f, 0.f, 0.f};
  int mbase = w * 16;
#pragma unroll
  for (int kk = 0; kk < KSTEPS; kk++) {
    int k = kk >> 1;
    int ci0 = (kk & 1) * 32;
    half8 a = *(const half8*)(sA + (mbase + nrow + k) * AP + ci0 + quad * 8);
#pragma unroll
    for (int ot = 0; ot < OCT; ot++) {
      half8 bb = *(const half8*)(sB + (ot * 16 + nrow) * BP + kk * 32 + quad * 8);
      acc[ot] = __builtin_amdgcn_mfma_f32_16x16x32_f16(a, bb, acc[ot], 0, 0, 0);
    }
  }
  // bn + leaky + pool, keep both pooled rows per lane
  float pA[OCT], pB[OCT];
  float sA1 = 0.f, sA2 = 0.f, sB1 = 0.f, sB2 = 0.f;
#pragma unroll
  for (int ot = 0; ot < OCT; ot++) {
    int oc = ot * 16 + nrow;
    float sc = g[oc] * rsqrtf(vr[oc] + EPS);
    float sh = bta[oc] - mn[oc] * sc;
    float v0 = acc[ot][0] * sc + sh, v1 = acc[ot][1] * sc + sh;
    float v2 = acc[ot][2] * sc + sh, v3 = acc[ot][3] * sc + sh;
    v0 = v0 >= 0.f ? v0 : 0.01f * v0;
    v1 = v1 >= 0.f ? v1 : 0.01f * v1;
    v2 = v2 >= 0.f ? v2 : 0.01f * v2;
    v3 = v3 >= 0.f ? v3 : 0.01f * v3;
    float a = fmaxf(v0, v1), bb2 = fmaxf(v2, v3);
    pA[ot] = a; pB[ot] = bb2;
    sA1 += a; sA2 += a * a; sB1 += bb2; sB2 += bb2 * bb2;
  }
#pragma unroll
  for (int m = 1; m <= 8; m <<= 1) {
    sA1 += __shfl_xor(sA1, m); sA2 += __shfl_xor(sA2, m);
    sB1 += __shfl_xor(sB1, m); sB2 += __shfl_xor(sB2, m);
  }
  float muA = sA1 * (1.f / 128.f);
  float rsA = rsqrtf(sA2 * (1.f / 128.f) - muA * muA + EPS);
  float muB = sB1 * (1.f / 128.f);
  float rsB = rsqrtf(sB2 * (1.f / 128.f) - muB * muB + EPS);
  int t0 = (p0 + mbase + quad * 4) >> 1, t1 = t0 + 1;
#pragma unroll
  for (int ot = 0; ot < OCT; ot++) {
    int oc = ot * 16 + nrow;
    float lw = lnw[oc];
    if (t0 < 510) xn[((size_t)b * 510 + t0) * OC + oc] = f16u((pA[ot] - muA) * rsA * lw);
    if (t1 < 510) xn[((size_t)b * 510 + t1) * OC + oc] = f16u((pB[ot] - muB) * rsB * lw);
    if (t1 == 509) elast[b * 128 + oc] = pB[ot];
  }
}

// ---------------- Fused dwconv+SiLU + gate projections via MFMA (f16) ----------------
// block = one (b,h). gx[s][bh][2l+slot] f16 (layout kRec expects).
__global__ __launch_bounds__(256) void kGxM(const unsigned short* __restrict__ xn,
    const float* __restrict__ cw, const float* __restrict__ cb,
    const float* __restrict__ wi, const float* __restrict__ wf,
    const float* __restrict__ wz, const float* __restrict__ wo,
    const float* __restrict__ rb, unsigned int* __restrict__ gx) {
  __shared__ __align__(16) char smem[29200];
  float* xnf = (float*)smem;                  // [66][33] fp32        (0..8712)
  _Float16* aX = (_Float16*)(smem + 8720);    // [64][40] f16 xcv
  _Float16* aN = (_Float16*)(smem + 13840);   // [64][40] f16 xn
  unsigned short* ct = (unsigned short*)smem; // [64][132] C-transpose (aliases above)
  _Float16* sW = (_Float16*)(smem + 18960);   // [2][64][40] weights
  int bh = blockIdx.x, b = bh >> 2, h = bh & 3;
  int tid = threadIdx.x, lane = tid & 63, w = tid >> 6;
  int nrow = lane & 15, quad = lane >> 4;
  for (int idx = tid; idx < 4096; idx += 256) {
    int slot = idx >> 11, n = (idx >> 5) & 63, d = idx & 31;
    const float* wp = slot ? ((n >= 32) ? wo : wz) : ((n >= 32) ? wf : wi);
    sW[slot * 2560 + n * 40 + d] = (_Float16)wp[h * 1024 + d * 32 + (n & 31)];
  }
  int dd = tid & 31;
  float cw0 = cw[(h * 32 + dd) * 3], cw1 = cw[(h * 32 + dd) * 3 + 1],
        cw2 = cw[(h * 32 + dd) * 3 + 2], cbv = cb[h * 32 + dd];
  float bias0[4], bias1[4];
#pragma unroll
  for (int nt = 0; nt < 4; nt++) {
    int n = nt * 16 + nrow;
    bias0[nt] = rb[(n >> 5) * 128 + h * 32 + (n & 31)];
    bias1[nt] = rb[(2 + (n >> 5)) * 128 + h * 32 + (n & 31)];
  }
  __syncthreads();
  half8 bw0[4], bw1[4];
#pragma unroll
  for (int nt = 0; nt < 4; nt++) {
    bw0[nt] = *(const half8*)(sW + (nt * 16 + nrow) * 40 + quad * 8);
    bw1[nt] = *(const half8*)(sW + 2560 + (nt * 16 + nrow) * 40 + quad * 8);
  }
  const unsigned short* xb = xn + ((size_t)b * 510) * 128 + h * 32;
  for (int s0 = 0; s0 < 510; s0 += 64) {
    __syncthreads();  // prev tile's ct fully copied
    {
      int d2 = tid & 15;
      for (int r = tid >> 4; r < 66; r += 16) {
        int s = s0 - 2 + r;
        unsigned int v = 0;
        if (s >= 0 && s < 510) v = *(const unsigned int*)(xb + (size_t)s * 128 + d2 * 2);
        xnf[r * 33 + d2 * 2]     = uf16(v & 0xFFFFu);
        xnf[r * 33 + d2 * 2 + 1] = uf16(v >> 16);
      }
    }
    __syncthreads();
    for (int m = tid >> 5; m < 64; m += 8) {
      float x0 = xnf[m * 33 + dd], x1 = xnf[(m + 1) * 33 + dd], x2 = xnf[(m + 2) * 33 + dd];
      float a = cbv + cw0 * x0 + cw1 * x1 + cw2 * x2;
      a = a * __builtin_amdgcn_rcpf(1.f + __expf(-a));
      aX[m * 40 + dd] = (_Float16)a;
      aN[m * 40 + dd] = (_Float16)x2;
    }
    __syncthreads();
    f32x4 z = (f32x4){0.f, 0.f, 0.f, 0.f};
    half8 ax = *(const half8*)(aX + (w * 16 + nrow) * 40 + quad * 8);
    half8 an = *(const half8*)(aN + (w * 16 + nrow) * 40 + quad * 8);
    f32x4 acc0[4], acc1[4];
#pragma unroll
    for (int nt = 0; nt < 4; nt++) {
      acc0[nt] = __builtin_amdgcn_mfma_f32_16x16x32_f16(ax, bw0[nt], z, 0, 0, 0);
      acc1[nt] = __builtin_amdgcn_mfma_f32_16x16x32_f16(an, bw1[nt], z, 0, 0, 0);
    }
    __syncthreads();  // A-frag reads drained before ct overwrite
#pragma unroll
    for (int nt = 0; nt < 4; nt++) {
#pragma unroll
      for (int r = 0; r < 4; r++) {
        int row = w * 16 + quad * 4 + r;
        ct[row * 132 + 2 * (nt * 16 + nrow)]     = f16u(acc0[nt][r] + bias0[nt]);
        ct[row * 132 + 2 * (nt * 16 + nrow) + 1] = f16u(acc1[nt][r] + bias1[nt]);
      }
    }
    __syncthreads();
    {
      int u = tid & 63;
      for (int m = tid >> 6; m < 64; m += 4) {
        int s = s0 + m;
        if (s < 510)
          gx[((size_t)s * 1024 + bh) * 64 + u] = *(const unsigned int*)(ct + m * 132 + 2 * u);
      }
    }
  }
}

// ---------------- Lean sLSTM recurrence: readlane y-broadcast; f16 gx unpack ----------------
__global__ __launch_bounds__(64) void kRec(const unsigned int* __restrict__ gx,
    const float* __restrict__ rk, float* __restrict__ yf) {
  int bh = blockIdx.x; int h = bh & 3;
  int l = threadIdx.x; int half = l >> 5; int e = l & 31;
  float R1[32], R2[32];
  int g1 = half, g2 = 2 + half;
  const float* r1p = rk + h * 4096 + g1 * 32 + e;
  const float* r2p = rk + h * 4096 + g2 * 32 + e;
#pragma unroll
  for (int d = 0; d < 32; d++) { R1[d] = r1p[d * 128]; R2[d] = r2p[d * 128]; }
  const unsigned int* gp = gx + (size_t)bh * 64 + l;
  unsigned int p0 = gp[0], p1 = gp[65536], p2 = gp[131072], p3 = gp[196608];
  float y = 0.f, cst = 0.f, nst = 0.f, mst = 0.f;
  for (int s = 0; s < 510; s++) {
    unsigned int pc = p0; p0 = p1; p1 = p2; p2 = p3;
    if (s + 4 < 510) p3 = gp[(size_t)(s + 4) * 65536];
    float a1 = uf16(pc & 0xFFFFu);   // pre (i/f)
    float a2 = uf16(pc >> 16);       // pre (z/o)
    float s10 = 0.f, s11 = 0.f, s12 = 0.f, s13 = 0.f;
    float s20 = 0.f, s21 = 0.f, s22 = 0.f, s23 = 0.f;
    unsigned int yb = __float_as_uint(y);
#pragma unroll
    for (int d = 0; d < 32; d += 4) {
      float y0 = __uint_as_float(__builtin_amdgcn_readlane(yb, d));
      float y1 = __uint_as_float(__builtin_amdgcn_readlane(yb, d + 1));
      float y2 = __uint_as_float(__builtin_amdgcn_readlane(yb, d + 2));
      float y3 = __uint_as_float(__builtin_amdgcn_readlane(yb, d + 3));
      s10 = fmaf(y0, R1[d], s10);     s20 = fmaf(y0, R2[d], s20);
      s11 = fmaf(y1, R1[d + 1], s11); s21 = fmaf(y1, R2[d + 1], s21);
      s12 = fmaf(y2, R1[d + 2], s12); s22 = fmaf(y2, R2[d + 2], s22);
      s13 = fmaf(y3, R1[d + 3], s13); s23 = fmaf(y3, R2[d + 3], s23);
    }
    a1 += (s10 + s11) + (s12 + s13);
    a2 += (s20 + s21) + (s22 + s23);
    float en = __expf(-fabsf(a1));
    float ls = fminf(a1, 0.f) - __logf(1.f + en);             // log-sigmoid(a1)
    float sg = __builtin_amdgcn_rcpf(1.f + __expf(-a2));      // sigmoid(a2)
    float tz = 1.f - 2.f * __builtin_amdgcn_rcpf(__expf(2.f * a2) + 1.f);  // tanh(a2)
    float lsf = __shfl_xor(ls, 32);
    float so  = __shfl_xor(sg, 32);
    float lf = mst + lsf;
    float mnew = fmaxf(a1, lf);
    float ig = __expf(a1 - mnew);
    float fg = __expf(lf - mnew);
    cst = fg * cst + ig * tz;
    nst = fg * nst + ig;
    mst = mnew;
    y = so * cst * __builtin_amdgcn_rcpf(nst);
  }
  if (half == 0) yf[(bh >> 2) * 128 + h * 32 + e] = y;
}

// ---------------- Tail for the last timestep only ----------------
__global__ __launch_bounds__(128) void kHead(const float* __restrict__ yf,
    const float* __restrict__ elast, const float* __restrict__ gnw,
    const float* __restrict__ ln2w, const float* __restrict__ upw,
    const float* __restrict__ dnw, const float* __restrict__ lnpw,
    const float* __restrict__ fcw, const float* __restrict__ fcb,
    float* __restrict__ outp) {
  int c = threadIdx.x; int b = blockIdx.x;
  __shared__ float sred[4];
  __shared__ float sx[128];
  __shared__ float sup[384];
  __shared__ float shh[192];
  float yv = yf[b * 128 + c];
  float s1 = yv, s2 = yv * yv;
#pragma unroll
  for (int m = 1; m <= 16; m <<= 1) { s1 += __shfl_xor(s1, m); s2 += __shfl_xor(s2, m); }
  float mu = s1 * (1.f / 32.f);
  float var = s2 * (1.f / 32.f) - mu * mu;
  float yn = (yv - mu) * rsqrtf(var + EPS) * gnw[c];
  float el = elast[b * 128 + c] + yn;
  auto ln128 = [&](float v, const float* w) -> float {
    float a = v, a2 = v * v;
#pragma unroll
    for (int m = 1; m <= 32; m <<= 1) { a += __shfl_xor(a, m); a2 += __shfl_xor(a2, m); }
    int wv = c >> 6;
    if ((c & 63) == 0) { sred[wv * 2] = a; sred[wv * 2 + 1] = a2; }
    __syncthreads();
    float t1 = sred[0] + sred[2], t2 = sred[1] + sred[3];
    __syncthreads();
    float mm = t1 * (1.f / 128.f);
    float vv = t2 * (1.f / 128.f) - mm * mm;
    return (v - mm) * rsqrtf(vv + EPS) * w[c];
  };
  float xn2 = ln128(el, ln2w);
  sx[c] = xn2;
  __syncthreads();
#pragma unroll
  for (int jj = 0; jj < 3; jj++) {
    int j = c + jj * 128;
    float acc = 0.f;
    for (int k = 0; k < 128; k++) acc += sx[k] * upw[k * 384 + j];
    sup[j] = acc;
  }
  __syncthreads();
  {
    float u = sup[c]; float mg = sup[192 + c];
    shh[c] = 0.5f * u * (1.f + erff(u * 0.70710678118654752f)) * mg;
    if (c < 64) {
      float u2 = sup[128 + c]; float m2 = sup[320 + c];
      shh[128 + c] = 0.5f * u2 * (1.f + erff(u2 * 0.70710678118654752f)) * m2;
    }
  }
  __syncthreads();
  float acc = 0.f;
  for (int f = 0; f < 192; f++) acc += shh[f] * dnw[f * 128 + c];
  float e2 = el + acc;
  float e3 = ln128(e2, lnpw);
  sx[c] = e3;
  __syncthreads();
  if (c < 5) {
    float a = fcb[c];
    for (int k = 0; k < 128; k++) a += sx[k] * fcw[k * 5 + c];
    outp[b * 5 + c] = a;
  }
}

extern "C" void kernel_launch(void* const* d_in, const int* in_sizes, int n_in,
                              void* d_out, int out_size, void* d_ws, size_t ws_size,
                              hipStream_t stream) {
  const float* x    = (const float*)d_in[0];
  const float* w1a  = (const float*)d_in[1];
  const float* w1b  = (const float*)d_in[2];
  const float* bn1g = (const float*)d_in[3];
  const float* bn1b = (const float*)d_in[4];
  const float* bn1m = (const float*)d_in[5];
  const float* bn1v = (const float*)d_in[6];
  const float* w2   = (const float*)d_in[7];
  const float* bn2g = (const float*)d_in[8];
  const float* bn2b = (const float*)d_in[9];
  const float* bn2m = (const float*)d_in[10];
  const float* bn2v = (const float*)d_in[11];
  const float* w3   = (const float*)d_in[12];
  const float* bn3g = (const float*)d_in[13];
  const float* bn3b = (const float*)d_in[14];
  const float* bn3m = (const float*)d_in[15];
  const float* bn3v = (const float*)d_in[16];
  const float* ln1w = (const float*)d_in[17];
  const float* cw   = (const float*)d_in[18];
  const float* cb   = (const float*)d_in[19];
  const float* wi   = (const float*)d_in[20];
  const float* wf   = (const float*)d_in[21];
  const float* wz   = (const float*)d_in[22];
  const float* wo   = (const float*)d_in[23];
  const float* rk   = (const float*)d_in[24];
  const float* rb   = (const float*)d_in[25];
  const float* gnw  = (const float*)d_in[26];
  const float* ln2w = (const float*)d_in[27];
  const float* upw  = (const float*)d_in[28];
  const float* dnw  = (const float*)d_in[29];
  const float* lnpw = (const float*)d_in[30];
  const float* fcw  = (const float*)d_in[31];
  const float* fcb  = (const float*)d_in[32];
  float* outp = (float*)d_out;

  // ---- Compacted workspace layout (total < 165 MB; previous layout needed
  // ~274 MB and wrote past a 256 MB workspace -> graph/single-launch tripwire).
  // Lifetimes: xnb  : written kConv3LN, read kGxM
  //            out2 : written kConv12,  read kConv3LN   (dead before kGxM)
  //            gxu  : written kGxM,     read kRec       -> may alias out2
  char* ws = (char*)d_ws;
  unsigned short* xnb  = (unsigned short*)ws;                           // [256][510][128] f16, 33,423,360 B
  unsigned short* out2 = (unsigned short*)(ws + ((size_t)34 << 20));    // [256][1022][64] f16, 33,488,896 B
  unsigned int*   gxu  = (unsigned int*)(ws + ((size_t)34 << 20));      // aliases out2 (disjoint lifetime), 133,693,440 B -> ends ~161.5 MB
  float* elast = (float*)(ws + ((size_t)162 << 20));                    // 131,072 B
  float* yfin  = (float*)(ws + ((size_t)163 << 20));                    // 131,072 B
  unsigned short* wtg2 = (unsigned short*)(ws + ((size_t)164 << 20));               // 13,312 B
  unsigned short* wtg3 = (unsigned short*)(ws + ((size_t)164 << 20) + (64 << 10));  // 51,200 B

  kWTB2<<<dim3(126), 256, 0, stream>>>(w2, w3, wtg2, wtg3);
  kConv12<<<dim3(16, 1, 256), 512, 0, stream>>>(
      x, w1a, w1b, bn1g, bn1b, bn1m, bn1v, wtg2, bn2g, bn2b, bn2m, bn2v, out2);
  kConv3LN<<<dim3(8, 1, 256), 512, 0, stream>>>(
      out2, wtg3, bn3g, bn3b, bn3m, bn3v, ln1w, xnb, elast);
  kGxM<<<dim3(1024), 256, 0, stream>>>(xnb, cw, cb, wi, wf, wz, wo, rb, gxu);
  kRec<<<dim3(1024), 64, 0, stream>>>(gxu, rk, yfin);
  kHead<<<dim3(256), 128, 0, stream>>>(yfin, elast, gnw, ln2w, upw, dnw, lnpw, fcw, fcb, outp);
}

// Round 3
// 553.041 us; speedup vs baseline: 1.0963x; 1.0963x over previous
//
#include <hip/hip_runtime.h>
#include <hip/hip_bf16.h>
#include <math.h>

#define EPS 1e-5f

typedef __attribute__((ext_vector_type(8))) _Float16 half8;
typedef __attribute__((ext_vector_type(4))) float f32x4;

static __device__ __forceinline__ unsigned short f16u(float x) {
  _Float16 h = (_Float16)x;  // RTN
  return *(unsigned short*)&h;
}
static __device__ __forceinline__ float uf16(unsigned short u) {
  _Float16 h = *(_Float16*)&u;
  return (float)h;
}

// ---------------- Combined weight transform for conv2+conv3: -> B^T f16 padded ----------------
__global__ __launch_bounds__(256) void kWTB2(const float* __restrict__ w2,
    const float* __restrict__ w3, unsigned short* __restrict__ o2,
    unsigned short* __restrict__ o3) {
  int idx = blockIdx.x * 256 + threadIdx.x;
  if (idx < 64 * 104) {
    int oc = idx / 104, kp = idx % 104;
    float v = 0.f;
    if (kp < 96) { int k = kp >> 5, ci = kp & 31; v = w2[oc * 96 + ci * 3 + k]; }
    o2[idx] = f16u(v);
  } else {
    int j = idx - 64 * 104;
    if (j < 128 * 200) {
      int oc = j / 200, kp = j % 200;
      float v = 0.f;
      if (kp < 192) { int k = kp >> 6, ci = kp & 63; v = w3[oc * 192 + ci * 3 + k]; }
      o3[j] = f16u(v);
    }
  }
}

// ---------------- Fused conv1(+bn1+leaky+pool) in-register + conv2 MFMA (+bn2+leaky+pool) ----------------
// x [256][4096][2] -> out2 f16 [256][1022][64]
__global__ __launch_bounds__(512) void kConv12(const float* __restrict__ x,
    const float* __restrict__ w1a, const float* __restrict__ w1b,
    const float* __restrict__ g1, const float* __restrict__ b1,
    const float* __restrict__ m1, const float* __restrict__ v1,
    const unsigned short* __restrict__ Bw, const float* __restrict__ g2,
    const float* __restrict__ b2, const float* __restrict__ m2,
    const float* __restrict__ v2, unsigned short* __restrict__ out2) {
  __shared__ _Float16 sA[130 * 40];
  __shared__ _Float16 sB[64 * 104];
  int tid = threadIdx.x;
  int b = blockIdx.z;
  int p0 = blockIdx.x * 128;  // conv2 pre-pool row base (= conv1-pooled row index)
  // stage conv2 weights
  {
    const unsigned int* src = (const unsigned int*)Bw;
    unsigned int* dst = (unsigned int*)sB;
    for (int i = tid; i < 64 * 104 / 2; i += 512) dst[i] = src[i];
  }
  // compute conv1 + bn1 + leaky + pool directly into sA (f16)
  {
    int c = tid & 31, rg = tid >> 5;  // rg in [0,16)
    float sc1 = g1[c] * rsqrtf(v1[c] + EPS);
    float sh1 = b1[c] - m1[c] * sc1;
    float wk0[4], wk1[4];
    if (c < 16) {
#pragma unroll
      for (int k = 0; k < 4; k++) { wk0[k] = w1a[c * 8 + k]; wk1[k] = w1a[c * 8 + 4 + k]; }
    } else {
      int cc = c - 16;
#pragma unroll
      for (int k = 0; k < 2; k++) { wk0[k] = w1b[cc * 4 + k]; wk1[k] = w1b[cc * 4 + 2 + k]; }
      wk0[2] = wk0[3] = wk1[2] = wk1[3] = 0.f;
    }
    const float2* xp = (const float2*)(x + (size_t)b * 8192);
    for (int r = rg; r < 130; r += 16) {
      int rr = p0 + r;
      _Float16 outv = (_Float16)0.f;
      if (rr < 2047) {
        float xv0[5], xv1[5];
#pragma unroll
        for (int j = 0; j < 5; j++) {
          int l = 2 * rr - 1 + j;
          if (l >= 0 && l < 4096) { float2 v = xp[l]; xv0[j] = v.x; xv1[j] = v.y; }
          else { xv0[j] = 0.f; xv1[j] = 0.f; }
        }
        float a0 = 0.f, a1 = 0.f;
        if (c < 16) {
#pragma unroll
          for (int k = 0; k < 4; k++) {
            a0 += xv0[k] * wk0[k] + xv1[k] * wk1[k];
            a1 += xv0[k + 1] * wk0[k] + xv1[k + 1] * wk1[k];
          }
        } else {
#pragma unroll
          for (int k = 0; k < 2; k++) {
            a0 += xv0[k + 1] * wk0[k] + xv1[k + 1] * wk1[k];
            a1 += xv0[k + 2] * wk0[k] + xv1[k + 2] * wk1[k];
          }
        }
        a0 = a0 * sc1 + sh1; a1 = a1 * sc1 + sh1;
        a0 = a0 >= 0.f ? a0 : 0.01f * a0;
        a1 = a1 >= 0.f ? a1 : 0.01f * a1;
        outv = (_Float16)fmaxf(a0, a1);
      }
      sA[r * 40 + c] = outv;
    }
  }
  __syncthreads();
  // conv2 MFMA: M=128 pre-pool rows, N=64, K=96
  int lane = tid & 63, w = tid >> 6;
  int nrow = lane & 15, quad = lane >> 4;
  f32x4 acc[4];
#pragma unroll
  for (int i = 0; i < 4; i++) acc[i] = (f32x4){0.f, 0.f, 0.f, 0.f};
  int mbase = w * 16;
#pragma unroll
  for (int kk = 0; kk < 3; kk++) {
    half8 a = *(const half8*)(sA + (mbase + nrow + kk) * 40 + quad * 8);
#pragma unroll
    for (int ot = 0; ot < 4; ot++) {
      half8 bb = *(const half8*)(sB + (ot * 16 + nrow) * 104 + kk * 32 + quad * 8);
      acc[ot] = __builtin_amdgcn_mfma_f32_16x16x32_f16(a, bb, acc[ot], 0, 0, 0);
    }
  }
  int gm0 = p0 + mbase + quad * 4;
#pragma unroll
  for (int ot = 0; ot < 4; ot++) {
    int oc = ot * 16 + nrow;
    float sc = g2[oc] * rsqrtf(v2[oc] + EPS);
    float sh = b2[oc] - m2[oc] * sc;
    float v0 = acc[ot][0] * sc + sh, vv1 = acc[ot][1] * sc + sh;
    float v2e = acc[ot][2] * sc + sh, v3 = acc[ot][3] * sc + sh;
    v0 = v0 >= 0.f ? v0 : 0.01f * v0;
    vv1 = vv1 >= 0.f ? vv1 : 0.01f * vv1;
    v2e = v2e >= 0.f ? v2e : 0.01f * v2e;
    v3 = v3 >= 0.f ? v3 : 0.01f * v3;
    float pA = fmaxf(v0, vv1), pB = fmaxf(v2e, v3);
    int t0 = gm0 >> 1, t1 = t0 + 1;
    if (t0 < 1022) out2[((size_t)b * 1022 + t0) * 64 + oc] = f16u(pA);
    if (t1 < 1022) out2[((size_t)b * 1022 + t1) * 64 + oc] = f16u(pB);
  }
}

// ---------------- MFMA conv3 + bn + leaky + pool + LayerNorm fused -> xn f16 [b][t][128], elast ----------------
__global__ __launch_bounds__(512) void kConv3LN(const unsigned short* __restrict__ in,
    const unsigned short* __restrict__ Bw, const float* __restrict__ g,
    const float* __restrict__ bta, const float* __restrict__ mn,
    const float* __restrict__ vr, const float* __restrict__ lnw,
    unsigned short* __restrict__ xn, float* __restrict__ elast) {
  constexpr int IC = 64, OC = 128, LIN = 1022, AP = 72, BP = 200, KSTEPS = 6, OCT = 8;
  __shared__ _Float16 sA[130 * AP];
  __shared__ _Float16 sB[OC * BP];
  int tid = threadIdx.x;
  int b = blockIdx.z;
  int p0 = blockIdx.x * 128;
  {
    const unsigned int* src = (const unsigned int*)Bw;
    unsigned int* dst = (unsigned int*)sB;
    for (int i = tid; i < OC * BP / 2; i += 512) dst[i] = src[i];
  }
  {
    int q = tid % 8;
    for (int r = tid / 8; r < 130; r += 64) {
      int gp = p0 + r;
      uint4 val = {0u, 0u, 0u, 0u};
      if (gp < LIN) val = *(const uint4*)(in + ((size_t)b * LIN + gp) * IC + q * 8);
      *(uint4*)(sA + r * AP + q * 8) = val;
    }
  }
  __syncthreads();
  int lane = tid & 63, w = tid >> 6;
  int nrow = lane & 15, quad = lane >> 4;
  f32x4 acc[OCT];
#pragma unroll
  for (int i = 0; i < OCT; i++) acc[i] = (f32x4){0.f, 0.f, 0.f, 0.f};
  int mbase = w * 16;
#pragma unroll
  for (int kk = 0; kk < KSTEPS; kk++) {
    int k = kk >> 1;
    int ci0 = (kk & 1) * 32;
    half8 a = *(const half8*)(sA + (mbase + nrow + k) * AP + ci0 + quad * 8);
#pragma unroll
    for (int ot = 0; ot < OCT; ot++) {
      half8 bb = *(const half8*)(sB + (ot * 16 + nrow) * BP + kk * 32 + quad * 8);
      acc[ot] = __builtin_amdgcn_mfma_f32_16x16x32_f16(a, bb, acc[ot], 0, 0, 0);
    }
  }
  // bn + leaky + pool, keep both pooled rows per lane
  float pA[OCT], pB[OCT];
  float sA1 = 0.f, sA2 = 0.f, sB1 = 0.f, sB2 = 0.f;
#pragma unroll
  for (int ot = 0; ot < OCT; ot++) {
    int oc = ot * 16 + nrow;
    float sc = g[oc] * rsqrtf(vr[oc] + EPS);
    float sh = bta[oc] - mn[oc] * sc;
    float v0 = acc[ot][0] * sc + sh, v1 = acc[ot][1] * sc + sh;
    float v2 = acc[ot][2] * sc + sh, v3 = acc[ot][3] * sc + sh;
    v0 = v0 >= 0.f ? v0 : 0.01f * v0;
    v1 = v1 >= 0.f ? v1 : 0.01f * v1;
    v2 = v2 >= 0.f ? v2 : 0.01f * v2;
    v3 = v3 >= 0.f ? v3 : 0.01f * v3;
    float a = fmaxf(v0, v1), bb2 = fmaxf(v2, v3);
    pA[ot] = a; pB[ot] = bb2;
    sA1 += a; sA2 += a * a; sB1 += bb2; sB2 += bb2 * bb2;
  }
#pragma unroll
  for (int m = 1; m <= 8; m <<= 1) {
    sA1 += __shfl_xor(sA1, m); sA2 += __shfl_xor(sA2, m);
    sB1 += __shfl_xor(sB1, m); sB2 += __shfl_xor(sB2, m);
  }
  float muA = sA1 * (1.f / 128.f);
  float rsA = rsqrtf(sA2 * (1.f / 128.f) - muA * muA + EPS);
  float muB = sB1 * (1.f / 128.f);
  float rsB = rsqrtf(sB2 * (1.f / 128.f) - muB * muB + EPS);
  int t0 = (p0 + mbase + quad * 4) >> 1, t1 = t0 + 1;
#pragma unroll
  for (int ot = 0; ot < OCT; ot++) {
    int oc = ot * 16 + nrow;
    float lw = lnw[oc];
    if (t0 < 510) xn[((size_t)b * 510 + t0) * OC + oc] = f16u((pA[ot] - muA) * rsA * lw);
    if (t1 < 510) xn[((size_t)b * 510 + t1) * OC + oc] = f16u((pB[ot] - muB) * rsB * lw);
    if (t1 == 509) elast[b * 128 + oc] = pB[ot];
  }
}

// ---------------- Fused dwconv+SiLU + gate projections via MFMA (f16) ----------------
// block = one (b,h). gx[s][bh][2l+slot] f16 (layout kRec expects).
__global__ __launch_bounds__(256) void kGxM(const unsigned short* __restrict__ xn,
    const float* __restrict__ cw, const float* __restrict__ cb,
    const float* __restrict__ wi, const float* __restrict__ wf,
    const float* __restrict__ wz, const float* __restrict__ wo,
    const float* __restrict__ rb, unsigned int* __restrict__ gx) {
  __shared__ __align__(16) char smem[29200];
  float* xnf = (float*)smem;                  // [66][33] fp32        (0..8712)
  _Float16* aX = (_Float16*)(smem + 8720);    // [64][40] f16 xcv
  _Float16* aN = (_Float16*)(smem + 13840);   // [64][40] f16 xn
  unsigned short* ct = (unsigned short*)smem; // [64][132] C-transpose (aliases above)
  _Float16* sW = (_Float16*)(smem + 18960);   // [2][64][40] weights
  int bh = blockIdx.x, b = bh >> 2, h = bh & 3;
  int tid = threadIdx.x, lane = tid & 63, w = tid >> 6;
  int nrow = lane & 15, quad = lane >> 4;
  for (int idx = tid; idx < 4096; idx += 256) {
    int slot = idx >> 11, n = (idx >> 5) & 63, d = idx & 31;
    const float* wp = slot ? ((n >= 32) ? wo : wz) : ((n >= 32) ? wf : wi);
    sW[slot * 2560 + n * 40 + d] = (_Float16)wp[h * 1024 + d * 32 + (n & 31)];
  }
  int dd = tid & 31;
  float cw0 = cw[(h * 32 + dd) * 3], cw1 = cw[(h * 32 + dd) * 3 + 1],
        cw2 = cw[(h * 32 + dd) * 3 + 2], cbv = cb[h * 32 + dd];
  float bias0[4], bias1[4];
#pragma unroll
  for (int nt = 0; nt < 4; nt++) {
    int n = nt * 16 + nrow;
    bias0[nt] = rb[(n >> 5) * 128 + h * 32 + (n & 31)];
    bias1[nt] = rb[(2 + (n >> 5)) * 128 + h * 32 + (n & 31)];
  }
  __syncthreads();
  half8 bw0[4], bw1[4];
#pragma unroll
  for (int nt = 0; nt < 4; nt++) {
    bw0[nt] = *(const half8*)(sW + (nt * 16 + nrow) * 40 + quad * 8);
    bw1[nt] = *(const half8*)(sW + 2560 + (nt * 16 + nrow) * 40 + quad * 8);
  }
  const unsigned short* xb = xn + ((size_t)b * 510) * 128 + h * 32;
  for (int s0 = 0; s0 < 510; s0 += 64) {
    __syncthreads();  // prev tile's ct fully copied
    {
      int d2 = tid & 15;
      for (int r = tid >> 4; r < 66; r += 16) {
        int s = s0 - 2 + r;
        unsigned int v = 0;
        if (s >= 0 && s < 510) v = *(const unsigned int*)(xb + (size_t)s * 128 + d2 * 2);
        xnf[r * 33 + d2 * 2]     = uf16(v & 0xFFFFu);
        xnf[r * 33 + d2 * 2 + 1] = uf16(v >> 16);
      }
    }
    __syncthreads();
    for (int m = tid >> 5; m < 64; m += 8) {
      float x0 = xnf[m * 33 + dd], x1 = xnf[(m + 1) * 33 + dd], x2 = xnf[(m + 2) * 33 + dd];
      float a = cbv + cw0 * x0 + cw1 * x1 + cw2 * x2;
      a = a * __builtin_amdgcn_rcpf(1.f + __expf(-a));
      aX[m * 40 + dd] = (_Float16)a;
      aN[m * 40 + dd] = (_Float16)x2;
    }
    __syncthreads();
    f32x4 z = (f32x4){0.f, 0.f, 0.f, 0.f};
    half8 ax = *(const half8*)(aX + (w * 16 + nrow) * 40 + quad * 8);
    half8 an = *(const half8*)(aN + (w * 16 + nrow) * 40 + quad * 8);
    f32x4 acc0[4], acc1[4];
#pragma unroll
    for (int nt = 0; nt < 4; nt++) {
      acc0[nt] = __builtin_amdgcn_mfma_f32_16x16x32_f16(ax, bw0[nt], z, 0, 0, 0);
      acc1[nt] = __builtin_amdgcn_mfma_f32_16x16x32_f16(an, bw1[nt], z, 0, 0, 0);
    }
    __syncthreads();  // A-frag reads drained before ct overwrite
#pragma unroll
    for (int nt = 0; nt < 4; nt++) {
#pragma unroll
      for (int r = 0; r < 4; r++) {
        int row = w * 16 + quad * 4 + r;
        ct[row * 132 + 2 * (nt * 16 + nrow)]     = f16u(acc0[nt][r] + bias0[nt]);
        ct[row * 132 + 2 * (nt * 16 + nrow) + 1] = f16u(acc1[nt][r] + bias1[nt]);
      }
    }
    __syncthreads();
    {
      int u = tid & 63;
      for (int m = tid >> 6; m < 64; m += 4) {
        int s = s0 + m;
        if (s < 510)
          gx[((size_t)s * 1024 + bh) * 64 + u] = *(const unsigned int*)(ct + m * 132 + 2 * u);
      }
    }
  }
}

// ---------------- Lean sLSTM recurrence ----------------
// 8-deep UNCONDITIONAL prefetch FIFO (clamped addresses) so the waitcnt pass
// can count vmcnt statically; the old `if (s+4<510)` conditional load forced a
// conservative per-iteration drain that exposed ~1100 cyc HBM latency per step.
__global__ __launch_bounds__(64) void kRec(const unsigned int* __restrict__ gx,
    const float* __restrict__ rk, float* __restrict__ yf) {
  int bh = blockIdx.x; int h = bh & 3;
  int l = threadIdx.x; int half = l >> 5; int e = l & 31;
  float R1[32], R2[32];
  int g1 = half, g2 = 2 + half;
  const float* r1p = rk + h * 4096 + g1 * 32 + e;
  const float* r2p = rk + h * 4096 + g2 * 32 + e;
#pragma unroll
  for (int d = 0; d < 32; d++) { R1[d] = r1p[d * 128]; R2[d] = r2p[d * 128]; }
  const unsigned int* gp = gx + (size_t)bh * 64 + l;
  unsigned int buf[8];
#pragma unroll
  for (int j = 0; j < 8; j++) buf[j] = gp[(size_t)j * 65536];
  float y = 0.f, cst = 0.f, nst = 0.f, mst = 0.f;

  auto step = [&](unsigned int pc) {
    float a1 = uf16(pc & 0xFFFFu);   // pre (i/f)
    float a2 = uf16(pc >> 16);       // pre (z/o)
    float s10 = 0.f, s11 = 0.f, s12 = 0.f, s13 = 0.f;
    float s20 = 0.f, s21 = 0.f, s22 = 0.f, s23 = 0.f;
    unsigned int yb = __float_as_uint(y);
#pragma unroll
    for (int d = 0; d < 32; d += 4) {
      float y0 = __uint_as_float(__builtin_amdgcn_readlane(yb, d));
      float y1 = __uint_as_float(__builtin_amdgcn_readlane(yb, d + 1));
      float y2 = __uint_as_float(__builtin_amdgcn_readlane(yb, d + 2));
      float y3 = __uint_as_float(__builtin_amdgcn_readlane(yb, d + 3));
      s10 = fmaf(y0, R1[d], s10);     s20 = fmaf(y0, R2[d], s20);
      s11 = fmaf(y1, R1[d + 1], s11); s21 = fmaf(y1, R2[d + 1], s21);
      s12 = fmaf(y2, R1[d + 2], s12); s22 = fmaf(y2, R2[d + 2], s22);
      s13 = fmaf(y3, R1[d + 3], s13); s23 = fmaf(y3, R2[d + 3], s23);
    }
    a1 += (s10 + s11) + (s12 + s13);
    a2 += (s20 + s21) + (s22 + s23);
    float en = __expf(-fabsf(a1));
    float ls = fminf(a1, 0.f) - __logf(1.f + en);             // log-sigmoid(a1)
    float sg = __builtin_amdgcn_rcpf(1.f + __expf(-a2));      // sigmoid(a2)
    float tz = 1.f - 2.f * __builtin_amdgcn_rcpf(__expf(2.f * a2) + 1.f);  // tanh(a2)
    float lsf = __shfl_xor(ls, 32);
    float so  = __shfl_xor(sg, 32);
    float lf = mst + lsf;
    float mnew = fmaxf(a1, lf);
    float ig = __expf(a1 - mnew);
    float fg = __expf(lf - mnew);
    cst = fg * cst + ig * tz;
    nst = fg * nst + ig;
    mst = mnew;
    y = so * cst * __builtin_amdgcn_rcpf(nst);
  };

  // main: 63 x 8 steps = 0..503, always 8 loads in flight (clamped addr at tail)
  for (int s0 = 0; s0 < 504; s0 += 8) {
#pragma unroll
    for (int j = 0; j < 8; j++) {
      unsigned int pc = buf[j];
      int sn = s0 + j + 8; sn = sn > 509 ? 509 : sn;
      buf[j] = gp[(size_t)sn * 65536];
      step(pc);
    }
  }
  // tail: steps 504..509 from buf[0..5], no further loads
#pragma unroll
  for (int j = 0; j < 6; j++) step(buf[j]);

  if (half == 0) yf[(bh >> 2) * 128 + h * 32 + e] = y;
}

// ---------------- Tail for the last timestep only ----------------
__global__ __launch_bounds__(128) void kHead(const float* __restrict__ yf,
    const float* __restrict__ elast, const float* __restrict__ gnw,
    const float* __restrict__ ln2w, const float* __restrict__ upw,
    const float* __restrict__ dnw, const float* __restrict__ lnpw,
    const float* __restrict__ fcw, const float* __restrict__ fcb,
    float* __restrict__ outp) {
  int c = threadIdx.x; int b = blockIdx.x;
  __shared__ float sred[4];
  __shared__ float sx[128];
  __shared__ float sup[384];
  __shared__ float shh[192];
  float yv = yf[b * 128 + c];
  float s1 = yv, s2 = yv * yv;
#pragma unroll
  for (int m = 1; m <= 16; m <<= 1) { s1 += __shfl_xor(s1, m); s2 += __shfl_xor(s2, m); }
  float mu = s1 * (1.f / 32.f);
  float var = s2 * (1.f / 32.f) - mu * mu;
  float yn = (yv - mu) * rsqrtf(var + EPS) * gnw[c];
  float el = elast[b * 128 + c] + yn;
  auto ln128 = [&](float v, const float* w) -> float {
    float a = v, a2 = v * v;
#pragma unroll
    for (int m = 1; m <= 32; m <<= 1) { a += __shfl_xor(a, m); a2 += __shfl_xor(a2, m); }
    int wv = c >> 6;
    if ((c & 63) == 0) { sred[wv * 2] = a; sred[wv * 2 + 1] = a2; }
    __syncthreads();
    float t1 = sred[0] + sred[2], t2 = sred[1] + sred[3];
    __syncthreads();
    float mm = t1 * (1.f / 128.f);
    float vv = t2 * (1.f / 128.f) - mm * mm;
    return (v - mm) * rsqrtf(vv + EPS) * w[c];
  };
  float xn2 = ln128(el, ln2w);
  sx[c] = xn2;
  __syncthreads();
#pragma unroll
  for (int jj = 0; jj < 3; jj++) {
    int j = c + jj * 128;
    float acc = 0.f;
    for (int k = 0; k < 128; k++) acc += sx[k] * upw[k * 384 + j];
    sup[j] = acc;
  }
  __syncthreads();
  {
    float u = sup[c]; float mg = sup[192 + c];
    shh[c] = 0.5f * u * (1.f + erff(u * 0.70710678118654752f)) * mg;
    if (c < 64) {
      float u2 = sup[128 + c]; float m2 = sup[320 + c];
      shh[128 + c] = 0.5f * u2 * (1.f + erff(u2 * 0.70710678118654752f)) * m2;
    }
  }
  __syncthreads();
  float acc = 0.f;
  for (int f = 0; f < 192; f++) acc += shh[f] * dnw[f * 128 + c];
  float e2 = el + acc;
  float e3 = ln128(e2, lnpw);
  sx[c] = e3;
  __syncthreads();
  if (c < 5) {
    float a = fcb[c];
    for (int k = 0; k < 128; k++) a += sx[k] * fcw[k * 5 + c];
    outp[b * 5 + c] = a;
  }
}

extern "C" void kernel_launch(void* const* d_in, const int* in_sizes, int n_in,
                              void* d_out, int out_size, void* d_ws, size_t ws_size,
                              hipStream_t stream) {
  const float* x    = (const float*)d_in[0];
  const float* w1a  = (const float*)d_in[1];
  const float* w1b  = (const float*)d_in[2];
  const float* bn1g = (const float*)d_in[3];
  const float* bn1b = (const float*)d_in[4];
  const float* bn1m = (const float*)d_in[5];
  const float* bn1v = (const float*)d_in[6];
  const float* w2   = (const float*)d_in[7];
  const float* bn2g = (const float*)d_in[8];
  const float* bn2b = (const float*)d_in[9];
  const float* bn2m = (const float*)d_in[10];
  const float* bn2v = (const float*)d_in[11];
  const float* w3   = (const float*)d_in[12];
  const float* bn3g = (const float*)d_in[13];
  const float* bn3b = (const float*)d_in[14];
  const float* bn3m = (const float*)d_in[15];
  const float* bn3v = (const float*)d_in[16];
  const float* ln1w = (const float*)d_in[17];
  const float* cw   = (const float*)d_in[18];
  const float* cb   = (const float*)d_in[19];
  const float* wi   = (const float*)d_in[20];
  const float* wf   = (const float*)d_in[21];
  const float* wz   = (const float*)d_in[22];
  const float* wo   = (const float*)d_in[23];
  const float* rk   = (const float*)d_in[24];
  const float* rb   = (const float*)d_in[25];
  const float* gnw  = (const float*)d_in[26];
  const float* ln2w = (const float*)d_in[27];
  const float* upw  = (const float*)d_in[28];
  const float* dnw  = (const float*)d_in[29];
  const float* lnpw = (const float*)d_in[30];
  const float* fcw  = (const float*)d_in[31];
  const float* fcb  = (const float*)d_in[32];
  float* outp = (float*)d_out;

  // ---- Compacted workspace layout (total < 165 MB).
  // Lifetimes: xnb  : written kConv3LN, read kGxM
  //            out2 : written kConv12,  read kConv3LN   (dead before kGxM)
  //            gxu  : written kGxM,     read kRec       -> may alias out2
  char* ws = (char*)d_ws;
  unsigned short* xnb  = (unsigned short*)ws;                           // [256][510][128] f16, 33,423,360 B
  unsigned short* out2 = (unsigned short*)(ws + ((size_t)34 << 20));    // [256][1022][64] f16, 33,488,896 B
  unsigned int*   gxu  = (unsigned int*)(ws + ((size_t)34 << 20));      // aliases out2 (disjoint lifetime), 133,693,440 B -> ends ~161.5 MB
  float* elast = (float*)(ws + ((size_t)162 << 20));                    // 131,072 B
  float* yfin  = (float*)(ws + ((size_t)163 << 20));                    // 131,072 B
  unsigned short* wtg2 = (unsigned short*)(ws + ((size_t)164 << 20));               // 13,312 B
  unsigned short* wtg3 = (unsigned short*)(ws + ((size_t)164 << 20) + (64 << 10));  // 51,200 B

  kWTB2<<<dim3(126), 256, 0, stream>>>(w2, w3, wtg2, wtg3);
  kConv12<<<dim3(16, 1, 256), 512, 0, stream>>>(
      x, w1a, w1b, bn1g, bn1b, bn1m, bn1v, wtg2, bn2g, bn2b, bn2m, bn2v, out2);
  kConv3LN<<<dim3(8, 1, 256), 512, 0, stream>>>(
      out2, wtg3, bn3g, bn3b, bn3m, bn3v, ln1w, xnb, elast);
  kGxM<<<dim3(1024), 256, 0, stream>>>(xnb, cw, cb, wi, wf, wz, wo, rb, gxu);
  kRec<<<dim3(1024), 64, 0, stream>>>(gxu, rk, yfin);
  kHead<<<dim3(256), 128, 0, stream>>>(yfin, elast, gnw, ln2w, upw, dnw, lnpw, fcw, fcb, outp);
}

// Round 7
// 533.490 us; speedup vs baseline: 1.1365x; 1.0366x over previous
//
#include <hip/hip_runtime.h>
#include <hip/hip_bf16.h>
#include <math.h>

#define EPS 1e-5f

typedef __attribute__((ext_vector_type(8))) _Float16 half8;
typedef __attribute__((ext_vector_type(4))) float f32x4;

static __device__ __forceinline__ unsigned short f16u(float x) {
  _Float16 h = (_Float16)x;  // RTN
  return *(unsigned short*)&h;
}
static __device__ __forceinline__ float uf16(unsigned short u) {
  _Float16 h = *(_Float16*)&u;
  return (float)h;
}

// ---------------- Combined weight transform for conv2+conv3: -> B^T f16 padded ----------------
__global__ __launch_bounds__(256) void kWTB2(const float* __restrict__ w2,
    const float* __restrict__ w3, unsigned short* __restrict__ o2,
    unsigned short* __restrict__ o3) {
  int idx = blockIdx.x * 256 + threadIdx.x;
  if (idx < 64 * 104) {
    int oc = idx / 104, kp = idx % 104;
    float v = 0.f;
    if (kp < 96) { int k = kp >> 5, ci = kp & 31; v = w2[oc * 96 + ci * 3 + k]; }
    o2[idx] = f16u(v);
  } else {
    int j = idx - 64 * 104;
    if (j < 128 * 200) {
      int oc = j / 200, kp = j % 200;
      float v = 0.f;
      if (kp < 192) { int k = kp >> 6, ci = kp & 63; v = w3[oc * 192 + ci * 3 + k]; }
      o3[j] = f16u(v);
    }
  }
}

// ---------------- Fused conv1(+bn1+leaky+pool) in-register + conv2 MFMA (+bn2+leaky+pool) ----------------
// x [256][4096][2] -> out2 f16 [256][1022][64]
__global__ __launch_bounds__(512) void kConv12(const float* __restrict__ x,
    const float* __restrict__ w1a, const float* __restrict__ w1b,
    const float* __restrict__ g1, const float* __restrict__ b1,
    const float* __restrict__ m1, const float* __restrict__ v1,
    const unsigned short* __restrict__ Bw, const float* __restrict__ g2,
    const float* __restrict__ b2, const float* __restrict__ m2,
    const float* __restrict__ v2, unsigned short* __restrict__ out2) {
  __shared__ _Float16 sA[130 * 40];
  __shared__ _Float16 sB[64 * 104];
  int tid = threadIdx.x;
  int b = blockIdx.z;
  int p0 = blockIdx.x * 128;  // conv2 pre-pool row base (= conv1-pooled row index)
  // stage conv2 weights
  {
    const unsigned int* src = (const unsigned int*)Bw;
    unsigned int* dst = (unsigned int*)sB;
    for (int i = tid; i < 64 * 104 / 2; i += 512) dst[i] = src[i];
  }
  // compute conv1 + bn1 + leaky + pool directly into sA (f16)
  {
    int c = tid & 31, rg = tid >> 5;  // rg in [0,16)
    float sc1 = g1[c] * rsqrtf(v1[c] + EPS);
    float sh1 = b1[c] - m1[c] * sc1;
    float wk0[4], wk1[4];
    if (c < 16) {
#pragma unroll
      for (int k = 0; k < 4; k++) { wk0[k] = w1a[c * 8 + k]; wk1[k] = w1a[c * 8 + 4 + k]; }
    } else {
      int cc = c - 16;
#pragma unroll
      for (int k = 0; k < 2; k++) { wk0[k] = w1b[cc * 4 + k]; wk1[k] = w1b[cc * 4 + 2 + k]; }
      wk0[2] = wk0[3] = wk1[2] = wk1[3] = 0.f;
    }
    const float2* xp = (const float2*)(x + (size_t)b * 8192);
    for (int r = rg; r < 130; r += 16) {
      int rr = p0 + r;
      _Float16 outv = (_Float16)0.f;
      if (rr < 2047) {
        float xv0[5], xv1[5];
#pragma unroll
        for (int j = 0; j < 5; j++) {
          int l = 2 * rr - 1 + j;
          if (l >= 0 && l < 4096) { float2 v = xp[l]; xv0[j] = v.x; xv1[j] = v.y; }
          else { xv0[j] = 0.f; xv1[j] = 0.f; }
        }
        float a0 = 0.f, a1 = 0.f;
        if (c < 16) {
#pragma unroll
          for (int k = 0; k < 4; k++) {
            a0 += xv0[k] * wk0[k] + xv1[k] * wk1[k];
            a1 += xv0[k + 1] * wk0[k] + xv1[k + 1] * wk1[k];
          }
        } else {
#pragma unroll
          for (int k = 0; k < 2; k++) {
            a0 += xv0[k + 1] * wk0[k] + xv1[k + 1] * wk1[k];
            a1 += xv0[k + 2] * wk0[k] + xv1[k + 2] * wk1[k];
          }
        }
        a0 = a0 * sc1 + sh1; a1 = a1 * sc1 + sh1;
        a0 = a0 >= 0.f ? a0 : 0.01f * a0;
        a1 = a1 >= 0.f ? a1 : 0.01f * a1;
        outv = (_Float16)fmaxf(a0, a1);
      }
      sA[r * 40 + c] = outv;
    }
  }
  __syncthreads();
  // conv2 MFMA: M=128 pre-pool rows, N=64, K=96
  int lane = tid & 63, w = tid >> 6;
  int nrow = lane & 15, quad = lane >> 4;
  f32x4 acc[4];
#pragma unroll
  for (int i = 0; i < 4; i++) acc[i] = (f32x4){0.f, 0.f, 0.f, 0.f};
  int mbase = w * 16;
#pragma unroll
  for (int kk = 0; kk < 3; kk++) {
    half8 a = *(const half8*)(sA + (mbase + nrow + kk) * 40 + quad * 8);
#pragma unroll
    for (int ot = 0; ot < 4; ot++) {
      half8 bb = *(const half8*)(sB + (ot * 16 + nrow) * 104 + kk * 32 + quad * 8);
      acc[ot] = __builtin_amdgcn_mfma_f32_16x16x32_f16(a, bb, acc[ot], 0, 0, 0);
    }
  }
  int gm0 = p0 + mbase + quad * 4;
#pragma unroll
  for (int ot = 0; ot < 4; ot++) {
    int oc = ot * 16 + nrow;
    float sc = g2[oc] * rsqrtf(v2[oc] + EPS);
    float sh = b2[oc] - m2[oc] * sc;
    float v0 = acc[ot][0] * sc + sh, vv1 = acc[ot][1] * sc + sh;
    float v2e = acc[ot][2] * sc + sh, v3 = acc[ot][3] * sc + sh;
    v0 = v0 >= 0.f ? v0 : 0.01f * v0;
    vv1 = vv1 >= 0.f ? vv1 : 0.01f * vv1;
    v2e = v2e >= 0.f ? v2e : 0.01f * v2e;
    v3 = v3 >= 0.f ? v3 : 0.01f * v3;
    float pA = fmaxf(v0, vv1), pB = fmaxf(v2e, v3);
    int t0 = gm0 >> 1, t1 = t0 + 1;
    if (t0 < 1022) out2[((size_t)b * 1022 + t0) * 64 + oc] = f16u(pA);
    if (t1 < 1022) out2[((size_t)b * 1022 + t1) * 64 + oc] = f16u(pB);
  }
}

// ---------------- MFMA conv3 + bn + leaky + pool + LayerNorm fused -> xn f16 [b][t][128], elast ----------------
__global__ __launch_bounds__(512) void kConv3LN(const unsigned short* __restrict__ in,
    const unsigned short* __restrict__ Bw, const float* __restrict__ g,
    const float* __restrict__ bta, const float* __restrict__ mn,
    const float* __restrict__ vr, const float* __restrict__ lnw,
    unsigned short* __restrict__ xn, float* __restrict__ elast) {
  constexpr int IC = 64, OC = 128, LIN = 1022, AP = 72, BP = 200, KSTEPS = 6, OCT = 8;
  __shared__ _Float16 sA[130 * AP];
  __shared__ _Float16 sB[OC * BP];
  int tid = threadIdx.x;
  int b = blockIdx.z;
  int p0 = blockIdx.x * 128;
  {
    const unsigned int* src = (const unsigned int*)Bw;
    unsigned int* dst = (unsigned int*)sB;
    for (int i = tid; i < OC * BP / 2; i += 512) dst[i] = src[i];
  }
  {
    int q = tid % 8;
    for (int r = tid / 8; r < 130; r += 64) {
      int gp = p0 + r;
      uint4 val = {0u, 0u, 0u, 0u};
      if (gp < LIN) val = *(const uint4*)(in + ((size_t)b * LIN + gp) * IC + q * 8);
      *(uint4*)(sA + r * AP + q * 8) = val;
    }
  }
  __syncthreads();
  int lane = tid & 63, w = tid >> 6;
  int nrow = lane & 15, quad = lane >> 4;
  f32x4 acc[OCT];
#pragma unroll
  for (int i = 0; i < OCT; i++) acc[i] = (f32x4){0.f, 0.f, 0.f, 0.f};
  int mbase = w * 16;
#pragma unroll
  for (int kk = 0; kk < KSTEPS; kk++) {
    int k = kk >> 1;
    int ci0 = (kk & 1) * 32;
    half8 a = *(const half8*)(sA + (mbase + nrow + k) * AP + ci0 + quad * 8);
#pragma unroll
    for (int ot = 0; ot < OCT; ot++) {
      half8 bb = *(const half8*)(sB + (ot * 16 + nrow) * BP + kk * 32 + quad * 8);
      acc[ot] = __builtin_amdgcn_mfma_f32_16x16x32_f16(a, bb, acc[ot], 0, 0, 0);
    }
  }
  // bn + leaky + pool, keep both pooled rows per lane
  float pA[OCT], pB[OCT];
  float sA1 = 0.f, sA2 = 0.f, sB1 = 0.f, sB2 = 0.f;
#pragma unroll
  for (int ot = 0; ot < OCT; ot++) {
    int oc = ot * 16 + nrow;
    float sc = g[oc] * rsqrtf(vr[oc] + EPS);
    float sh = bta[oc] - mn[oc] * sc;
    float v0 = acc[ot][0] * sc + sh, v1 = acc[ot][1] * sc + sh;
    float v2 = acc[ot][2] * sc + sh, v3 = acc[ot][3] * sc + sh;
    v0 = v0 >= 0.f ? v0 : 0.01f * v0;
    v1 = v1 >= 0.f ? v1 : 0.01f * v1;
    v2 = v2 >= 0.f ? v2 : 0.01f * v2;
    v3 = v3 >= 0.f ? v3 : 0.01f * v3;
    float a = fmaxf(v0, v1), bb2 = fmaxf(v2, v3);
    pA[ot] = a; pB[ot] = bb2;
    sA1 += a; sA2 += a * a; sB1 += bb2; sB2 += bb2 * bb2;
  }
#pragma unroll
  for (int m = 1; m <= 8; m <<= 1) {
    sA1 += __shfl_xor(sA1, m); sA2 += __shfl_xor(sA2, m);
    sB1 += __shfl_xor(sB1, m); sB2 += __shfl_xor(sB2, m);
  }
  float muA = sA1 * (1.f / 128.f);
  float rsA = rsqrtf(sA2 * (1.f / 128.f) - muA * muA + EPS);
  float muB = sB1 * (1.f / 128.f);
  float rsB = rsqrtf(sB2 * (1.f / 128.f) - muB * muB + EPS);
  int t0 = (p0 + mbase + quad * 4) >> 1, t1 = t0 + 1;
#pragma unroll
  for (int ot = 0; ot < OCT; ot++) {
    int oc = ot * 16 + nrow;
    float lw = lnw[oc];
    if (t0 < 510) xn[((size_t)b * 510 + t0) * OC + oc] = f16u((pA[ot] - muA) * rsA * lw);
    if (t1 < 510) xn[((size_t)b * 510 + t1) * OC + oc] = f16u((pB[ot] - muB) * rsB * lw);
    if (t1 == 509) elast[b * 128 + oc] = pB[ot];
  }
}

// ---------------- Fused dwconv+SiLU + gate projections via MFMA (f16) ----------------
// Phase-windowed: computes s in [sBeg, sEnd) and writes gx/gxlo indexed by
// (s - sBeg), so a 256-step window needs only 96 MiB instead of 200 MiB
// (workspace cap is between 165 and 228 MiB — 228 MiB layout tripwired as OOB).
// Pair word gx[sL][bh][l] = a1_hi16 | a2_f16<<16 ; gxlo holds a1 low 16 bits
// -> a1 (i/f preactivation) stored EXACTLY in f32 (verified: absmax 0.047).
__global__ __launch_bounds__(256) void kGxM(const unsigned short* __restrict__ xn,
    const float* __restrict__ cw, const float* __restrict__ cb,
    const float* __restrict__ wi, const float* __restrict__ wf,
    const float* __restrict__ wz, const float* __restrict__ wo,
    const float* __restrict__ rb, unsigned int* __restrict__ gx,
    unsigned short* __restrict__ gxlo, int sBeg, int sEnd) {
  __shared__ __align__(16) char smem[37904];
  float* xnf = (float*)smem;                  // [66][33] fp32        (0..8712)
  _Float16* aX = (_Float16*)(smem + 8720);    // [64][40] f16 xcv
  _Float16* aN = (_Float16*)(smem + 13840);   // [64][40] f16 xn
  unsigned short* ct = (unsigned short*)smem; // [64][132] C-transpose (aliases above)
  _Float16* sW = (_Float16*)(smem + 18960);   // [2][64][40] weights
  unsigned short* ct2 = (unsigned short*)(smem + 29200);  // [64][68] a1-lo bits
  int bh = blockIdx.x, b = bh >> 2, h = bh & 3;
  int tid = threadIdx.x, lane = tid & 63, w = tid >> 6;
  int nrow = lane & 15, quad = lane >> 4;
  for (int idx = tid; idx < 4096; idx += 256) {
    int slot = idx >> 11, n = (idx >> 5) & 63, d = idx & 31;
    const float* wp = slot ? ((n >= 32) ? wo : wz) : ((n >= 32) ? wf : wi);
    sW[slot * 2560 + n * 40 + d] = (_Float16)wp[h * 1024 + d * 32 + (n & 31)];
  }
  int dd = tid & 31;
  float cw0 = cw[(h * 32 + dd) * 3], cw1 = cw[(h * 32 + dd) * 3 + 1],
        cw2 = cw[(h * 32 + dd) * 3 + 2], cbv = cb[h * 32 + dd];
  float bias0[4], bias1[4];
#pragma unroll
  for (int nt = 0; nt < 4; nt++) {
    int n = nt * 16 + nrow;
    bias0[nt] = rb[(n >> 5) * 128 + h * 32 + (n & 31)];
    bias1[nt] = rb[(2 + (n >> 5)) * 128 + h * 32 + (n & 31)];
  }
  __syncthreads();
  half8 bw0[4], bw1[4];
#pragma unroll
  for (int nt = 0; nt < 4; nt++) {
    bw0[nt] = *(const half8*)(sW + (nt * 16 + nrow) * 40 + quad * 8);
    bw1[nt] = *(const half8*)(sW + 2560 + (nt * 16 + nrow) * 40 + quad * 8);
  }
  const unsigned short* xb = xn + ((size_t)b * 510) * 128 + h * 32;
  for (int s0 = sBeg; s0 < sEnd; s0 += 64) {
    __syncthreads();  // prev tile's ct/ct2 fully copied
    {
      int d2 = tid & 15;
      for (int r = tid >> 4; r < 66; r += 16) {
        int s = s0 - 2 + r;
        unsigned int v = 0;
        if (s >= 0 && s < 510) v = *(const unsigned int*)(xb + (size_t)s * 128 + d2 * 2);
        xnf[r * 33 + d2 * 2]     = uf16(v & 0xFFFFu);
        xnf[r * 33 + d2 * 2 + 1] = uf16(v >> 16);
      }
    }
    __syncthreads();
    for (int m = tid >> 5; m < 64; m += 8) {
      float x0 = xnf[m * 33 + dd], x1 = xnf[(m + 1) * 33 + dd], x2 = xnf[(m + 2) * 33 + dd];
      float a = cbv + cw0 * x0 + cw1 * x1 + cw2 * x2;
      a = a * __builtin_amdgcn_rcpf(1.f + __expf(-a));
      aX[m * 40 + dd] = (_Float16)a;
      aN[m * 40 + dd] = (_Float16)x2;
    }
    __syncthreads();
    f32x4 z = (f32x4){0.f, 0.f, 0.f, 0.f};
    half8 ax = *(const half8*)(aX + (w * 16 + nrow) * 40 + quad * 8);
    half8 an = *(const half8*)(aN + (w * 16 + nrow) * 40 + quad * 8);
    f32x4 acc0[4], acc1[4];
#pragma unroll
    for (int nt = 0; nt < 4; nt++) {
      acc0[nt] = __builtin_amdgcn_mfma_f32_16x16x32_f16(ax, bw0[nt], z, 0, 0, 0);
      acc1[nt] = __builtin_amdgcn_mfma_f32_16x16x32_f16(an, bw1[nt], z, 0, 0, 0);
    }
    __syncthreads();  // A-frag reads drained before ct overwrite
#pragma unroll
    for (int nt = 0; nt < 4; nt++) {
#pragma unroll
      for (int r = 0; r < 4; r++) {
        int row = w * 16 + quad * 4 + r;
        int n = nt * 16 + nrow;
        float A1 = acc0[nt][r] + bias0[nt];
        unsigned int ab = __float_as_uint(A1);
        ct[row * 132 + 2 * n]     = (unsigned short)(ab >> 16);
        ct[row * 132 + 2 * n + 1] = f16u(acc1[nt][r] + bias1[nt]);
        ct2[row * 68 + n]         = (unsigned short)(ab & 0xFFFFu);
      }
    }
    __syncthreads();
    {
      int u = tid & 63;
      for (int m = tid >> 6; m < 64; m += 4) {
        int s = s0 + m;
        if (s < sEnd) {
          size_t ri = ((size_t)(s - sBeg) * 1024 + bh) * 64 + u;
          gx[ri]   = *(const unsigned int*)(ct + m * 132 + 2 * u);
          gxlo[ri] = ct2[m * 68 + u];
        }
      }
    }
  }
}

// ---------------- Lean sLSTM recurrence (phase-windowed) ----------------
// a1 reconstructed exactly: a1 = as_float((pair<<16) | lo). a2 = f16(pair>>16).
// 8-deep unconditional prefetch FIFOs; __launch_bounds__(64,1): grid = 1024
// waves = 1/SIMD, occupancy >1 unreachable -> full VGPR file, keep R1/R2
// architectural. State (y,c,n,m) carried through f32 buffer between phases
// (exact handoff; arithmetic identical to single-pass version).
template <int NS, bool FIRST, bool LAST>
__global__ __launch_bounds__(64, 1) void kRecT(const unsigned int* __restrict__ gx,
    const unsigned short* __restrict__ gxlo,
    const float* __restrict__ rk, float* __restrict__ st, float* __restrict__ yf) {
  int bh = blockIdx.x; int h = bh & 3;
  int l = threadIdx.x; int half = l >> 5; int e = l & 31;
  float R1[32], R2[32];
  int g1 = half, g2 = 2 + half;
  const float* r1p = rk + h * 4096 + g1 * 32 + e;
  const float* r2p = rk + h * 4096 + g2 * 32 + e;
#pragma unroll
  for (int d = 0; d < 32; d++) { R1[d] = r1p[d * 128]; R2[d] = r2p[d * 128]; }
  const unsigned int* gp = gx + (size_t)bh * 64 + l;
  const unsigned short* glp = gxlo + (size_t)bh * 64 + l;
  unsigned int buf[8];
  unsigned short bl[8];
#pragma unroll
  for (int j = 0; j < 8; j++) { buf[j] = gp[(size_t)j * 65536]; bl[j] = glp[(size_t)j * 65536]; }
  int sidx = bh * 64 + l;
  float y, cst, nst, mst;
  if (FIRST) {
    y = 0.f; cst = 0.f; nst = 0.f; mst = 0.f;
  } else {
    y = st[sidx]; cst = st[65536 + sidx]; nst = st[131072 + sidx]; mst = st[196608 + sidx];
  }

  auto step = [&](unsigned int pc, unsigned short lo) {
    float a1 = __uint_as_float((pc << 16) | (unsigned int)lo);  // exact f32 i/f pre
    float a2 = uf16((unsigned short)(pc >> 16));                // f16 z/o pre
    float s10 = 0.f, s11 = 0.f, s12 = 0.f, s13 = 0.f;
    float s20 = 0.f, s21 = 0.f, s22 = 0.f, s23 = 0.f;
    unsigned int yb = __float_as_uint(y);
#pragma unroll
    for (int d = 0; d < 32; d += 4) {
      float y0 = __uint_as_float(__builtin_amdgcn_readlane(yb, d));
      float y1 = __uint_as_float(__builtin_amdgcn_readlane(yb, d + 1));
      float y2 = __uint_as_float(__builtin_amdgcn_readlane(yb, d + 2));
      float y3 = __uint_as_float(__builtin_amdgcn_readlane(yb, d + 3));
      s10 = fmaf(y0, R1[d], s10);     s20 = fmaf(y0, R2[d], s20);
      s11 = fmaf(y1, R1[d + 1], s11); s21 = fmaf(y1, R2[d + 1], s21);
      s12 = fmaf(y2, R1[d + 2], s12); s22 = fmaf(y2, R2[d + 2], s22);
      s13 = fmaf(y3, R1[d + 3], s13); s23 = fmaf(y3, R2[d + 3], s23);
    }
    a1 += (s10 + s11) + (s12 + s13);
    a2 += (s20 + s21) + (s22 + s23);
    float en = __expf(-fabsf(a1));
    float ls = fminf(a1, 0.f) - __logf(1.f + en);             // log-sigmoid(a1)
    float sg = __builtin_amdgcn_rcpf(1.f + __expf(-a2));      // sigmoid(a2)
    float tz = 1.f - 2.f * __builtin_amdgcn_rcpf(__expf(2.f * a2) + 1.f);  // tanh(a2)
    float lsf = __shfl_xor(ls, 32);
    float so  = __shfl_xor(sg, 32);
    float lf = mst + lsf;
    float mnew = fmaxf(a1, lf);
    float ig = __expf(a1 - mnew);
    float fg = __expf(lf - mnew);
    cst = fg * cst + ig * tz;
    nst = fg * nst + ig;
    mst = mnew;
    y = so * cst * __builtin_amdgcn_rcpf(nst);
  };

  constexpr int NSF = NS & ~7;  // full 8-blocks
  // main: steps 0..NSF-9, loads always in range — never clamps
  for (int s0 = 0; s0 < NSF - 8; s0 += 8) {
#pragma unroll
    for (int j = 0; j < 8; j++) {
      unsigned int pc = buf[j]; unsigned short lo = bl[j];
      buf[j] = gp[(size_t)(s0 + j + 8) * 65536];
      bl[j]  = glp[(size_t)(s0 + j + 8) * 65536];
      step(pc, lo);
    }
  }
  // steps NSF-8..NSF-1, loads NSF..NSF+7 clamped to NS-1 (dups never consumed)
#pragma unroll
  for (int j = 0; j < 8; j++) {
    unsigned int pc = buf[j]; unsigned short lo = bl[j];
    int sn = NSF + j; sn = sn > NS - 1 ? NS - 1 : sn;
    buf[j] = gp[(size_t)sn * 65536];
    bl[j]  = glp[(size_t)sn * 65536];
    step(pc, lo);
  }
  // tail: steps NSF..NS-1 from buf[0..NS-NSF-1], no further loads
#pragma unroll
  for (int j = 0; j < NS - NSF; j++) step(buf[j], bl[j]);

  if (LAST) {
    if (half == 0) yf[(bh >> 2) * 128 + h * 32 + e] = y;
  } else {
    st[sidx] = y; st[65536 + sidx] = cst; st[131072 + sidx] = nst; st[196608 + sidx] = mst;
  }
}

// ---------------- Tail for the last timestep only ----------------
__global__ __launch_bounds__(128) void kHead(const float* __restrict__ yf,
    const float* __restrict__ elast, const float* __restrict__ gnw,
    const float* __restrict__ ln2w, const float* __restrict__ upw,
    const float* __restrict__ dnw, const float* __restrict__ lnpw,
    const float* __restrict__ fcw, const float* __restrict__ fcb,
    float* __restrict__ outp) {
  int c = threadIdx.x; int b = blockIdx.x;
  __shared__ float sred[4];
  __shared__ float sx[128];
  __shared__ float sup[384];
  __shared__ float shh[192];
  float yv = yf[b * 128 + c];
  float s1 = yv, s2 = yv * yv;
#pragma unroll
  for (int m = 1; m <= 16; m <<= 1) { s1 += __shfl_xor(s1, m); s2 += __shfl_xor(s2, m); }
  float mu = s1 * (1.f / 32.f);
  float var = s2 * (1.f / 32.f) - mu * mu;
  float yn = (yv - mu) * rsqrtf(var + EPS) * gnw[c];
  float el = elast[b * 128 + c] + yn;
  auto ln128 = [&](float v, const float* w) -> float {
    float a = v, a2 = v * v;
#pragma unroll
    for (int m = 1; m <= 32; m <<= 1) { a += __shfl_xor(a, m); a2 += __shfl_xor(a2, m); }
    int wv = c >> 6;
    if ((c & 63) == 0) { sred[wv * 2] = a; sred[wv * 2 + 1] = a2; }
    __syncthreads();
    float t1 = sred[0] + sred[2], t2 = sred[1] + sred[3];
    __syncthreads();
    float mm = t1 * (1.f / 128.f);
    float vv = t2 * (1.f / 128.f) - mm * mm;
    return (v - mm) * rsqrtf(vv + EPS) * w[c];
  };
  float xn2 = ln128(el, ln2w);
  sx[c] = xn2;
  __syncthreads();
#pragma unroll
  for (int jj = 0; jj < 3; jj++) {
    int j = c + jj * 128;
    float acc = 0.f;
    for (int k = 0; k < 128; k++) acc += sx[k] * upw[k * 384 + j];
    sup[j] = acc;
  }
  __syncthreads();
  {
    float u = sup[c]; float mg = sup[192 + c];
    shh[c] = 0.5f * u * (1.f + erff(u * 0.70710678118654752f)) * mg;
    if (c < 64) {
      float u2 = sup[128 + c]; float m2 = sup[320 + c];
      shh[128 + c] = 0.5f * u2 * (1.f + erff(u2 * 0.70710678118654752f)) * m2;
    }
  }
  __syncthreads();
  float acc = 0.f;
  for (int f = 0; f < 192; f++) acc += shh[f] * dnw[f * 128 + c];
  float e2 = el + acc;
  float e3 = ln128(e2, lnpw);
  sx[c] = e3;
  __syncthreads();
  if (c < 5) {
    float a = fcb[c];
    for (int k = 0; k < 128; k++) a += sx[k] * fcw[k * 5 + c];
    outp[b * 5 + c] = a;
  }
}

extern "C" void kernel_launch(void* const* d_in, const int* in_sizes, int n_in,
                              void* d_out, int out_size, void* d_ws, size_t ws_size,
                              hipStream_t stream) {
  const float* x    = (const float*)d_in[0];
  const float* w1a  = (const float*)d_in[1];
  const float* w1b  = (const float*)d_in[2];
  const float* bn1g = (const float*)d_in[3];
  const float* bn1b = (const float*)d_in[4];
  const float* bn1m = (const float*)d_in[5];
  const float* bn1v = (const float*)d_in[6];
  const float* w2   = (const float*)d_in[7];
  const float* bn2g = (const float*)d_in[8];
  const float* bn2b = (const float*)d_in[9];
  const float* bn2m = (const float*)d_in[10];
  const float* bn2v = (const float*)d_in[11];
  const float* w3   = (const float*)d_in[12];
  const float* bn3g = (const float*)d_in[13];
  const float* bn3b = (const float*)d_in[14];
  const float* bn3m = (const float*)d_in[15];
  const float* bn3v = (const float*)d_in[16];
  const float* ln1w = (const float*)d_in[17];
  const float* cw   = (const float*)d_in[18];
  const float* cb   = (const float*)d_in[19];
  const float* wi   = (const float*)d_in[20];
  const float* wf   = (const float*)d_in[21];
  const float* wz   = (const float*)d_in[22];
  const float* wo   = (const float*)d_in[23];
  const float* rk   = (const float*)d_in[24];
  const float* rb   = (const float*)d_in[25];
  const float* gnw  = (const float*)d_in[26];
  const float* ln2w = (const float*)d_in[27];
  const float* upw  = (const float*)d_in[28];
  const float* dnw  = (const float*)d_in[29];
  const float* lnpw = (const float*)d_in[30];
  const float* fcw  = (const float*)d_in[31];
  const float* fcb  = (const float*)d_in[32];
  float* outp = (float*)d_out;

  // ---- Workspace layout, high-water ~133 MiB (< known-good 164 MiB cap).
  // Lifetimes: xnb  : written kConv3LN, read kGxM (both phases)
  //            out2 : written kConv12,  read kConv3LN  -> dead before kGxM,
  //                   aliases the gx pair window
  //            gxu/gxlo: 256-step window, written kGxM_p, read kRec_p,
  //                   reused across the two phases
  char* ws = (char*)d_ws;
  unsigned short* xnb  = (unsigned short*)ws;                           // 33,423,360 B
  unsigned short* out2 = (unsigned short*)(ws + ((size_t)34 << 20));    // 33,488,896 B (aliases gxu)
  unsigned int*   gxu  = (unsigned int*)(ws + ((size_t)34 << 20));      // 64 MiB window: 34..98 MiB
  unsigned short* gxlo = (unsigned short*)(ws + ((size_t)98 << 20));    // 32 MiB window: 98..130 MiB
  float* st    = (float*)(ws + ((size_t)130 << 20));                    // 1 MiB state (y,c,n,m)
  float* elast = (float*)(ws + ((size_t)131 << 20));                    // 131,072 B
  float* yfin  = (float*)(ws + ((size_t)132 << 20));                    // 131,072 B
  unsigned short* wtg2 = (unsigned short*)(ws + ((size_t)133 << 20));               // 13,312 B
  unsigned short* wtg3 = (unsigned short*)(ws + ((size_t)133 << 20) + (64 << 10));  // 51,200 B

  kWTB2<<<dim3(126), 256, 0, stream>>>(w2, w3, wtg2, wtg3);
  kConv12<<<dim3(16, 1, 256), 512, 0, stream>>>(
      x, w1a, w1b, bn1g, bn1b, bn1m, bn1v, wtg2, bn2g, bn2b, bn2m, bn2v, out2);
  kConv3LN<<<dim3(8, 1, 256), 512, 0, stream>>>(
      out2, wtg3, bn3g, bn3b, bn3m, bn3v, ln1w, xnb, elast);
  // Phase A: steps [0, 256)
  kGxM<<<dim3(1024), 256, 0, stream>>>(xnb, cw, cb, wi, wf, wz, wo, rb, gxu, gxlo, 0, 256);
  kRecT<256, true, false><<<dim3(1024), 64, 0, stream>>>(gxu, gxlo, rk, st, yfin);
  // Phase B: steps [256, 510)
  kGxM<<<dim3(1024), 256, 0, stream>>>(xnb, cw, cb, wi, wf, wz, wo, rb, gxu, gxlo, 256, 510);
  kRecT<254, false, true><<<dim3(1024), 64, 0, stream>>>(gxu, gxlo, rk, st, yfin);
  kHead<<<dim3(256), 128, 0, stream>>>(yfin, elast, gnw, ln2w, upw, dnw, lnpw, fcw, fcb, outp);
}